// Round 16
// baseline (196.405 us; speedup 1.0000x reference)
//
#include <hip/hip_runtime.h>

#define N_NODES 50000
#define N_EDGES 800000
#define EDIM 16
#define NEG_SLOPE 0.2f

typedef _Float16 f16x8 __attribute__((ext_vector_type(8)));
typedef _Float16 f16x4 __attribute__((ext_vector_type(4)));
typedef _Float16 f16x2 __attribute__((ext_vector_type(2)));
typedef float f32x4 __attribute__((ext_vector_type(4)));

// ============================ CSR build ============================
// custom zero (the runtime's fillBufferAligned for this buffer measured 40 us!)
__global__ void zero_cnt_kernel(int* __restrict__ cnt) {
    int gid = blockIdx.x * blockDim.x + threadIdx.x;
    if (gid < N_NODES) cnt[gid] = 0;
}

// count + per-edge rank (the atomic's return value IS the rank within dst)
__global__ void count_rank_kernel(const int* __restrict__ ei, int* __restrict__ cnt,
                                  int* __restrict__ rank) {
    int e = blockIdx.x * blockDim.x + threadIdx.x;
    if (e < N_EDGES) rank[e] = atomicAdd(&cnt[ei[N_EDGES + e]], 1);
}

__global__ void scan_block_kernel(const int* __restrict__ in, int* __restrict__ excl,
                                  int* __restrict__ bsums, int n) {
    __shared__ int sh[256];
    int tid = threadIdx.x;
    int gid = blockIdx.x * 256 + tid;
    int v = (gid < n) ? in[gid] : 0;
    sh[tid] = v;
    __syncthreads();
    for (int off = 1; off < 256; off <<= 1) {
        int t = (tid >= off) ? sh[tid - off] : 0;
        __syncthreads();
        sh[tid] += t;
        __syncthreads();
    }
    if (gid < n) excl[gid] = sh[tid] - v;
    if (bsums != nullptr && tid == 255) bsums[blockIdx.x] = sh[tid];
}

__global__ void scan_add_kernel(const int* __restrict__ excl, const int* __restrict__ bs2,
                                int* __restrict__ csr_off, int n, int total) {
    int gid = blockIdx.x * 256 + threadIdx.x;
    if (gid < n) csr_off[gid] = excl[gid] + bs2[gid >> 8];
    if (gid == 0) csr_off[n] = total;
}

// w_e layout: [0:16) l1h0, [16:32) l1h1, [32:48) l2h0, [48:64) l2h1
__global__ void we2_kernel(const float* __restrict__ We1, const float* __restrict__ ae1,
                           const float* __restrict__ We2, const float* __restrict__ ae2,
                           float* __restrict__ w_e) {
    int idx = threadIdx.x;
    if (idx >= 64) return;
    const float* We = (idx < 32) ? We1 : We2;
    const float* ae = (idx < 32) ? ae1 : ae2;
    int i = idx & 31;
    int h = i >> 4, d = i & 15;
    float s = 0.f;
    for (int c = 0; c < 64; ++c) s += We[d * 128 + h * 64 + c] * ae[h * 64 + c];
    w_e[idx] = s;
}

// atomic-free scatter: pos = csr_off[d] + rank[e]; ONE packed 16B record per edge
// rec = {src, f16x2(ae1 h0,h1), f16x2(ae2 h0,h1), 0}
__global__ void scatter_pack_kernel(const int* __restrict__ ei, const float* __restrict__ edge_attr,
                                    const float* __restrict__ w_e, const int* __restrict__ csr_off,
                                    const int* __restrict__ rank, uint4* __restrict__ recs) {
    int e = blockIdx.x * blockDim.x + threadIdx.x;
    if (e >= N_EDGES) return;
    int s = ei[e];
    int d = ei[N_EDGES + e];
    const float* ea = edge_attr + (size_t)e * 16;
    float4 dd = make_float4(0.f, 0.f, 0.f, 0.f);
#pragma unroll
    for (int q = 0; q < 4; ++q) {
        float4 v = *reinterpret_cast<const float4*>(ea + q * 4);
        float4 wa = *reinterpret_cast<const float4*>(w_e + q * 4);
        float4 wb = *reinterpret_cast<const float4*>(w_e + 16 + q * 4);
        float4 wc = *reinterpret_cast<const float4*>(w_e + 32 + q * 4);
        float4 wd = *reinterpret_cast<const float4*>(w_e + 48 + q * 4);
        dd.x += v.x * wa.x + v.y * wa.y + v.z * wa.z + v.w * wa.w;
        dd.y += v.x * wb.x + v.y * wb.y + v.z * wb.z + v.w * wb.w;
        dd.z += v.x * wc.x + v.y * wc.y + v.z * wc.z + v.w * wc.w;
        dd.w += v.x * wd.x + v.y * wd.y + v.z * wd.z + v.w * wd.w;
    }
    f16x2 p1 = {(_Float16)dd.x, (_Float16)dd.y};
    f16x2 p2 = {(_Float16)dd.z, (_Float16)dd.w};
    int pos = csr_off[d] + rank[e];
    uint4 rec;
    rec.x = (unsigned)s;
    rec.y = __builtin_bit_cast(unsigned int, p1);
    rec.z = __builtin_bit_cast(unsigned int, p2);
    rec.w = 0u;
    recs[pos] = rec;
}

// ============================ fused MFMA GEMM + attdot ============================
// H = X[M,K] @ W[K,128]; X read as f32 (cast) or f16 per F16IN. Writes H16 + a_src/a_dst.
// Layouts (guide §3, m89/m156): A: row=lane&15, k=8*(lane>>4)+j
//                               B: col=lane&15, k=8*(lane>>4)+j
//                               D: col=lane&15, row=4*(lane>>4)+reg
template <int K, bool F16IN>
__global__ __launch_bounds__(256) void gemm_att_kernel(const void* __restrict__ Xv,
                                                       const float* __restrict__ W,
                                                       const float* __restrict__ as_,
                                                       const float* __restrict__ ad_,
                                                       _Float16* __restrict__ H16,
                                                       float2* __restrict__ a_src,
                                                       float2* __restrict__ a_dst, int M) {
    constexpr int NCH = K / 32;
    __shared__ _Float16 wlds[8 * NCH * 64 * 8];  // [ct][chunk][lane][j]
    const int tid = threadIdx.x;

    for (int idx = tid; idx < K * 128; idx += 256) {
        int k = idx >> 7, c = idx & 127;
        int ct = c >> 4, cl = c & 15;
        int chunk = k >> 5, grp = (k >> 3) & 3, j = k & 7;
        wlds[(((ct * NCH) + chunk) * 64 + (grp * 16 + cl)) * 8 + j] = (_Float16)W[idx];
    }
    __syncthreads();

    const int wv = tid >> 6, lane = tid & 63;
    const int lcol = lane & 15, lgrp = lane >> 4;
    const int row0 = blockIdx.x * 64 + wv * 16;
    int arow = row0 + lcol;
    if (arow >= M) arow = M - 1;

    f32x4 acc[8];
#pragma unroll
    for (int ct = 0; ct < 8; ++ct) acc[ct] = (f32x4){0.f, 0.f, 0.f, 0.f};

#pragma unroll
    for (int chunk = 0; chunk < NCH; ++chunk) {
        f16x8 afrag;
        if constexpr (F16IN) {
            const _Float16* aptr = (const _Float16*)Xv + (size_t)arow * K + lgrp * 8;
            afrag = *reinterpret_cast<const f16x8*>(aptr + chunk * 32);
        } else {
            const float* aptr = (const float*)Xv + (size_t)arow * K + lgrp * 8;
            float4 va = *reinterpret_cast<const float4*>(aptr + chunk * 32);
            float4 vb = *reinterpret_cast<const float4*>(aptr + chunk * 32 + 4);
            afrag = (f16x8){(_Float16)va.x, (_Float16)va.y, (_Float16)va.z, (_Float16)va.w,
                            (_Float16)vb.x, (_Float16)vb.y, (_Float16)vb.z, (_Float16)vb.w};
        }
#pragma unroll
        for (int ct = 0; ct < 8; ++ct) {
            f16x8 bfrag = *reinterpret_cast<const f16x8*>(&wlds[((ct * NCH + chunk) * 64 + lane) * 8]);
            acc[ct] = __builtin_amdgcn_mfma_f32_16x16x32_f16(afrag, bfrag, acc[ct], 0, 0, 0);
        }
    }

    float asv[8], adv[8];
#pragma unroll
    for (int ct = 0; ct < 8; ++ct) {
        asv[ct] = as_[ct * 16 + lcol];
        adv[ct] = ad_[ct * 16 + lcol];
    }

#pragma unroll
    for (int r = 0; r < 4; ++r) {
        int grow = row0 + lgrp * 4 + r;
        float s0 = 0.f, s1 = 0.f, d0 = 0.f, d1 = 0.f;
#pragma unroll
        for (int ct = 0; ct < 8; ++ct) {
            float v = acc[ct][r];
            if (grow < M) H16[(size_t)grow * 128 + ct * 16 + lcol] = (_Float16)v;
            if (ct < 4) { s0 += v * asv[ct]; d0 += v * adv[ct]; }
            else        { s1 += v * asv[ct]; d1 += v * adv[ct]; }
        }
#pragma unroll
        for (int m = 1; m < 16; m <<= 1) {
            s0 += __shfl_xor(s0, m);
            s1 += __shfl_xor(s1, m);
            d0 += __shfl_xor(d0, m);
            d1 += __shfl_xor(d1, m);
        }
        if (lcol == 0 && grow < M) {
            a_src[grow] = make_float2(s0, s1);
            a_dst[grow] = make_float2(d0, d1);
        }
    }
}

// ============================ fused logit + aggregate + self-mean ============================
// R13/R15 structure (2 subgroups x 32 lanes, lane = f16x4 / 8B gather, 2 edges per stage)
// with DEPTH-6 rotating prefetch (pA..pF, named regs, rule #20): ~12 gathers in flight
// per wave for this latency-bound loop. den accumulated in-loop from the head-selected
// broadcast and folded into the single shfl_xor(32) subgroup combine. Self-loop terms
// added ONCE, post-combine (R12 lesson). ex-broadcast slot sl_ <= 63 never wraps; slots
// >= m read inactive lanes' ex = 0. Prefetch slot (sl_+12)&63 may wrap: address is
// valid (some lane's sv or n), and its contribution is zeroed by the ex=0 guard.
#define AGG_STAGE(PREG, II)                                                        \
    do {                                                                           \
        int sl_ = 2 * (II) + sub;                                                  \
        float e0b_ = __shfl(ex0, sl_);                                             \
        float e1b_ = __shfl(ex1, sl_);                                             \
        float exu_ = h1sel ? e1b_ : e0b_;                                          \
        int svn_ = __shfl(sv, (sl_ + 12) & 63);                                    \
        den += exu_;                                                               \
        acc0 = fmaf(exu_, (float)PREG.x, acc0);                                    \
        acc1 = fmaf(exu_, (float)PREG.y, acc1);                                    \
        acc2 = fmaf(exu_, (float)PREG.z, acc2);                                    \
        acc3 = fmaf(exu_, (float)PREG.w, acc3);                                    \
        PREG = *reinterpret_cast<const f16x4*>(hb + ((size_t)(unsigned)svn_ << 8)); \
    } while (0)

__global__ void aggregate_kernel(const int* __restrict__ csr_off, const uint4* __restrict__ recs,
                                 const float2* __restrict__ a_src, const float2* __restrict__ a_dst,
                                 const _Float16* __restrict__ H16, const float* __restrict__ bias,
                                 float* __restrict__ out32, _Float16* __restrict__ out16,
                                 int layer, int do_relu) {
    int wid = (blockIdx.x * blockDim.x + threadIdx.x) >> 6;
    int lane = threadIdx.x & 63;
    if (wid >= N_NODES) return;
    const int n = wid;
    const int q = lane & 31;       // channel-slot group: f16 indices q*4..q*4+3
    const int sub = lane >> 5;     // which edge of the pair
    const bool h1sel = q >= 16;    // slots 64..127 = head1
    const char* hb = reinterpret_cast<const char*>(H16) + q * 8;

    float2 adn = a_dst[n];
    float2 asn = a_src[n];
    int b = csr_off[n], e = csr_off[n + 1];

    float acc0 = 0.f, acc1 = 0.f, acc2 = 0.f, acc3 = 0.f;
    float den = 0.f;
    float sae0 = 0.f, sae1 = 0.f;

    for (int base = b; base < e; base += 64) {
        int j = base + lane;
        bool act = j < e;
        int sv = n;
        float ex0 = 0.f, ex1 = 0.f;
        if (act) {
            uint4 rec = recs[j];
            sv = (int)rec.x;
            unsigned aeu = layer ? rec.z : rec.y;
            f16x2 aev = __builtin_bit_cast(f16x2, aeu);
            float ael0 = (float)aev.x, ael1 = (float)aev.y;
            sae0 += ael0;
            sae1 += ael1;
            float2 asv = a_src[sv];
            float q0 = asv.x + adn.x + ael0;
            float q1 = asv.y + adn.y + ael1;
            q0 = (q0 > 0.f) ? q0 : NEG_SLOPE * q0;
            q1 = (q1 > 0.f) ? q1 : NEG_SLOPE * q1;
            ex0 = __expf(q0);
            ex1 = __expf(q1);
        }

        int m = e - base;
        if (m > 64) m = 64;
        int nit = (m + 1) >> 1;  // 2 edges per stage
        f16x4 pA, pB, pC, pD, pE, pF;
        int s_;
        s_ = __shfl(sv, sub);      pA = *reinterpret_cast<const f16x4*>(hb + ((size_t)(unsigned)s_ << 8));
        s_ = __shfl(sv, 2 + sub);  pB = *reinterpret_cast<const f16x4*>(hb + ((size_t)(unsigned)s_ << 8));
        s_ = __shfl(sv, 4 + sub);  pC = *reinterpret_cast<const f16x4*>(hb + ((size_t)(unsigned)s_ << 8));
        s_ = __shfl(sv, 6 + sub);  pD = *reinterpret_cast<const f16x4*>(hb + ((size_t)(unsigned)s_ << 8));
        s_ = __shfl(sv, 8 + sub);  pE = *reinterpret_cast<const f16x4*>(hb + ((size_t)(unsigned)s_ << 8));
        s_ = __shfl(sv, 10 + sub); pF = *reinterpret_cast<const f16x4*>(hb + ((size_t)(unsigned)s_ << 8));
        for (int i = 0; i < nit; i += 6) {
            AGG_STAGE(pA, i);
            AGG_STAGE(pB, i + 1);
            AGG_STAGE(pC, i + 2);
            AGG_STAGE(pD, i + 3);
            AGG_STAGE(pE, i + 4);
            AGG_STAGE(pF, i + 5);
        }
    }

    // combine the two sub-groups FIRST (disjoint edge halves); den rides along
    acc0 += __shfl_xor(acc0, 32);
    acc1 += __shfl_xor(acc1, 32);
    acc2 += __shfl_xor(acc2, 32);
    acc3 += __shfl_xor(acc3, 32);
    den += __shfl_xor(den, 32);

    // self-loop: ae_self = mean of incoming ae (0 if no edges); added ONCE, post-combine
#pragma unroll
    for (int m2 = 32; m2; m2 >>= 1) {
        sae0 += __shfl_xor(sae0, m2);
        sae1 += __shfl_xor(sae1, m2);
    }
    int deg = e - b;
    float invd = (deg > 0) ? (1.f / (float)deg) : 0.f;
    float l0 = asn.x + adn.x + sae0 * invd;
    float l1 = asn.y + adn.y + sae1 * invd;
    l0 = (l0 > 0.f) ? l0 : NEG_SLOPE * l0;
    l1 = (l1 > 0.f) ? l1 : NEG_SLOPE * l1;
    float exs0 = __expf(l0), exs1 = __expf(l1);
    float exsu = h1sel ? exs1 : exs0;
    den += exsu;
    f16x4 hs = *reinterpret_cast<const f16x4*>(hb + ((size_t)(unsigned)n << 8));
    acc0 = fmaf(exsu, (float)hs.x, acc0);
    acc1 = fmaf(exsu, (float)hs.y, acc1);
    acc2 = fmaf(exsu, (float)hs.z, acc2);
    acc3 = fmaf(exsu, (float)hs.w, acc3);

    float invden = 1.f / (den + 1e-16f);
    float r0 = acc0 * invden;
    float r1 = acc1 * invden;
    float r2 = acc2 * invden;
    float r3 = acc3 * invden;
    // head combine: lane q<16 (head0 ch q*4..+3) pairs with lane q+16 (head1 same ch)
    float t0 = __shfl_xor(r0, 16);
    float t1 = __shfl_xor(r1, 16);
    float t2 = __shfl_xor(r2, 16);
    float t3 = __shfl_xor(r3, 16);
    if (lane < 16) {
        float4 bv = *reinterpret_cast<const float4*>(bias + q * 4);
        float o0 = 0.5f * (r0 + t0) + bv.x;
        float o1 = 0.5f * (r1 + t1) + bv.y;
        float o2 = 0.5f * (r2 + t2) + bv.z;
        float o3 = 0.5f * (r3 + t3) + bv.w;
        if (do_relu) {
            o0 = fmaxf(o0, 0.f); o1 = fmaxf(o1, 0.f);
            o2 = fmaxf(o2, 0.f); o3 = fmaxf(o3, 0.f);
        }
        if (out32) {
            float4 ov = {o0, o1, o2, o3};
            *reinterpret_cast<float4*>(out32 + (size_t)n * 64 + q * 4) = ov;
        }
        if (out16) {
            f16x4 ov16 = {(_Float16)o0, (_Float16)o1, (_Float16)o2, (_Float16)o3};
            *reinterpret_cast<f16x4*>(out16 + (size_t)n * 64 + q * 4) = ov16;
        }
    }
}

// ============================ launch ============================
extern "C" void kernel_launch(void* const* d_in, const int* in_sizes, int n_in,
                              void* d_out, int out_size, void* d_ws, size_t ws_size,
                              hipStream_t stream) {
    const float* x = (const float*)d_in[0];
    const int* ei = (const int*)d_in[1];
    const float* edge_attr = (const float*)d_in[2];
    const float* W1 = (const float*)d_in[3];
    const float* We1 = (const float*)d_in[4];
    const float* as1 = (const float*)d_in[5];
    const float* ad1 = (const float*)d_in[6];
    const float* ae1 = (const float*)d_in[7];
    const float* b1 = (const float*)d_in[8];
    const float* W2 = (const float*)d_in[9];
    const float* We2 = (const float*)d_in[10];
    const float* as2 = (const float*)d_in[11];
    const float* ad2 = (const float*)d_in[12];
    const float* ae2 = (const float*)d_in[13];
    const float* b2 = (const float*)d_in[14];
    float* out = (float*)d_out;

    char* ws = (char*)d_ws;
    size_t off = 0;
    auto alloc = [&](size_t bytes) -> void* {
        void* p = ws + off;
        off += (bytes + 255) & ~(size_t)255;
        return p;
    };
    int* cnt = (int*)alloc((size_t)N_NODES * 4);
    int* csr_off = (int*)alloc(((size_t)N_NODES + 1) * 4);
    int* rank = (int*)alloc((size_t)N_EDGES * 4);
    int* excl = (int*)alloc((size_t)N_NODES * 4);
    int* bsums = (int*)alloc(256 * 4);
    int* bsums2 = (int*)alloc(256 * 4);
    uint4* recs = (uint4*)alloc((size_t)N_EDGES * 16);
    _Float16* H16 = (_Float16*)alloc((size_t)N_NODES * 128 * 2);
    _Float16* h1_16 = (_Float16*)alloc((size_t)N_NODES * 64 * 2);
    float* a_src = (float*)alloc((size_t)N_NODES * 2 * 4);
    float* a_dst = (float*)alloc((size_t)N_NODES * 2 * 4);
    float* w_e = (float*)alloc(64 * 4);

    const int nb = (N_NODES + 255) / 256;
    const int eb = (N_EDGES + 255) / 256;

    // ---- CSR (atomic only in count; its return value = rank) ----
    zero_cnt_kernel<<<nb, 256, 0, stream>>>(cnt);
    we2_kernel<<<1, 64, 0, stream>>>(We1, ae1, We2, ae2, w_e);
    count_rank_kernel<<<eb, 256, 0, stream>>>(ei, cnt, rank);
    scan_block_kernel<<<nb, 256, 0, stream>>>(cnt, excl, bsums, N_NODES);
    scan_block_kernel<<<1, 256, 0, stream>>>(bsums, bsums2, nullptr, nb);
    scan_add_kernel<<<nb, 256, 0, stream>>>(excl, bsums2, csr_off, N_NODES, N_EDGES);
    scatter_pack_kernel<<<eb, 256, 0, stream>>>(ei, edge_attr, w_e, csr_off, rank, recs);

    const int nodeWaveBlocks = (N_NODES * 64 + 255) / 256;
    const int gemmBlocks = (N_NODES + 63) / 64;

    // ---- layer 1: IN=128 -> HID=64, H=2, relu; h1 written f16 only ----
    gemm_att_kernel<128, false><<<gemmBlocks, 256, 0, stream>>>(x, W1, as1, ad1, H16,
                                                                (float2*)a_src, (float2*)a_dst, N_NODES);
    aggregate_kernel<<<nodeWaveBlocks, 256, 0, stream>>>(csr_off, recs,
                                                         (const float2*)a_src, (const float2*)a_dst,
                                                         H16, b1, nullptr, h1_16, 0, 1);

    // ---- layer 2: HID=64 -> OUT=64, H=2, no relu ----
    gemm_att_kernel<64, true><<<gemmBlocks, 256, 0, stream>>>(h1_16, W2, as2, ad2, H16,
                                                              (float2*)a_src, (float2*)a_dst, N_NODES);
    aggregate_kernel<<<nodeWaveBlocks, 256, 0, stream>>>(csr_off, recs,
                                                         (const float2*)a_src, (const float2*)a_dst,
                                                         H16, b2, out, nullptr, 1, 0);
}

// Round 17
// 183.855 us; speedup vs baseline: 1.0683x; 1.0683x over previous
//
#include <hip/hip_runtime.h>

#define N_NODES 50000
#define N_EDGES 800000
#define EDIM 16
#define NEG_SLOPE 0.2f

typedef _Float16 f16x8 __attribute__((ext_vector_type(8)));
typedef _Float16 f16x4 __attribute__((ext_vector_type(4)));
typedef _Float16 f16x2 __attribute__((ext_vector_type(2)));
typedef float f32x4 __attribute__((ext_vector_type(4)));

// ============================ CSR build ============================
// zero cnt + compute w_e in one launch (block 0, lanes 0-63 do w_e)
// w_e layout: [0:16) l1h0, [16:32) l1h1, [32:48) l2h0, [48:64) l2h1
__global__ void zero_we2_kernel(int* __restrict__ cnt,
                                const float* __restrict__ We1, const float* __restrict__ ae1,
                                const float* __restrict__ We2, const float* __restrict__ ae2,
                                float* __restrict__ w_e) {
    int gid = blockIdx.x * blockDim.x + threadIdx.x;
    if (gid < N_NODES) cnt[gid] = 0;
    if (blockIdx.x == 0 && threadIdx.x < 64) {
        int idx = threadIdx.x;
        const float* We = (idx < 32) ? We1 : We2;
        const float* ae = (idx < 32) ? ae1 : ae2;
        int i = idx & 31;
        int h = i >> 4, d = i & 15;
        float s = 0.f;
        for (int c = 0; c < 64; ++c) s += We[d * 128 + h * 64 + c] * ae[h * 64 + c];
        w_e[idx] = s;
    }
}

// count + per-edge rank (the atomic's return value IS the rank within dst)
__global__ void count_rank_kernel(const int* __restrict__ ei, int* __restrict__ cnt,
                                  int* __restrict__ rank) {
    int e = blockIdx.x * blockDim.x + threadIdx.x;
    if (e < N_EDGES) rank[e] = atomicAdd(&cnt[ei[N_EDGES + e]], 1);
}

__global__ void scan_block_kernel(const int* __restrict__ in, int* __restrict__ excl,
                                  int* __restrict__ bsums, int n) {
    __shared__ int sh[256];
    int tid = threadIdx.x;
    int gid = blockIdx.x * 256 + tid;
    int v = (gid < n) ? in[gid] : 0;
    sh[tid] = v;
    __syncthreads();
    for (int off = 1; off < 256; off <<= 1) {
        int t = (tid >= off) ? sh[tid - off] : 0;
        __syncthreads();
        sh[tid] += t;
        __syncthreads();
    }
    if (gid < n) excl[gid] = sh[tid] - v;
    if (bsums != nullptr && tid == 255) bsums[blockIdx.x] = sh[tid];
}

__global__ void scan_add_kernel(const int* __restrict__ excl, const int* __restrict__ bs2,
                                int* __restrict__ csr_off, int n, int total) {
    int gid = blockIdx.x * 256 + threadIdx.x;
    if (gid < n) csr_off[gid] = excl[gid] + bs2[gid >> 8];
    if (gid == 0) csr_off[n] = total;
}

// atomic-free scatter: pos = csr_off[d] + rank[e]; ONE packed 16B record per edge
// rec = {src, f16x2(ae1 h0,h1), f16x2(ae2 h0,h1), 0}
__global__ void scatter_pack_kernel(const int* __restrict__ ei, const float* __restrict__ edge_attr,
                                    const float* __restrict__ w_e, const int* __restrict__ csr_off,
                                    const int* __restrict__ rank, uint4* __restrict__ recs) {
    int e = blockIdx.x * blockDim.x + threadIdx.x;
    if (e >= N_EDGES) return;
    int s = ei[e];
    int d = ei[N_EDGES + e];
    const float* ea = edge_attr + (size_t)e * 16;
    float4 dd = make_float4(0.f, 0.f, 0.f, 0.f);
#pragma unroll
    for (int q = 0; q < 4; ++q) {
        float4 v = *reinterpret_cast<const float4*>(ea + q * 4);
        float4 wa = *reinterpret_cast<const float4*>(w_e + q * 4);
        float4 wb = *reinterpret_cast<const float4*>(w_e + 16 + q * 4);
        float4 wc = *reinterpret_cast<const float4*>(w_e + 32 + q * 4);
        float4 wd = *reinterpret_cast<const float4*>(w_e + 48 + q * 4);
        dd.x += v.x * wa.x + v.y * wa.y + v.z * wa.z + v.w * wa.w;
        dd.y += v.x * wb.x + v.y * wb.y + v.z * wb.z + v.w * wb.w;
        dd.z += v.x * wc.x + v.y * wc.y + v.z * wc.z + v.w * wc.w;
        dd.w += v.x * wd.x + v.y * wd.y + v.z * wd.z + v.w * wd.w;
    }
    f16x2 p1 = {(_Float16)dd.x, (_Float16)dd.y};
    f16x2 p2 = {(_Float16)dd.z, (_Float16)dd.w};
    int pos = csr_off[d] + rank[e];
    uint4 rec;
    rec.x = (unsigned)s;
    rec.y = __builtin_bit_cast(unsigned int, p1);
    rec.z = __builtin_bit_cast(unsigned int, p2);
    rec.w = 0u;
    recs[pos] = rec;
}

// ============================ fused MFMA GEMM + attdot ============================
// H = X[M,K] @ W[K,128]; X read as f32 (cast) or f16 per F16IN. Writes H16 + a_src/a_dst.
// Layouts (guide §3, m89/m156): A: row=lane&15, k=8*(lane>>4)+j
//                               B: col=lane&15, k=8*(lane>>4)+j
//                               D: col=lane&15, row=4*(lane>>4)+reg
template <int K, bool F16IN>
__global__ __launch_bounds__(256) void gemm_att_kernel(const void* __restrict__ Xv,
                                                       const float* __restrict__ W,
                                                       const float* __restrict__ as_,
                                                       const float* __restrict__ ad_,
                                                       _Float16* __restrict__ H16,
                                                       float2* __restrict__ a_src,
                                                       float2* __restrict__ a_dst, int M) {
    constexpr int NCH = K / 32;
    __shared__ _Float16 wlds[8 * NCH * 64 * 8];  // [ct][chunk][lane][j]
    const int tid = threadIdx.x;

    for (int idx = tid; idx < K * 128; idx += 256) {
        int k = idx >> 7, c = idx & 127;
        int ct = c >> 4, cl = c & 15;
        int chunk = k >> 5, grp = (k >> 3) & 3, j = k & 7;
        wlds[(((ct * NCH) + chunk) * 64 + (grp * 16 + cl)) * 8 + j] = (_Float16)W[idx];
    }
    __syncthreads();

    const int wv = tid >> 6, lane = tid & 63;
    const int lcol = lane & 15, lgrp = lane >> 4;
    const int row0 = blockIdx.x * 64 + wv * 16;
    int arow = row0 + lcol;
    if (arow >= M) arow = M - 1;

    f32x4 acc[8];
#pragma unroll
    for (int ct = 0; ct < 8; ++ct) acc[ct] = (f32x4){0.f, 0.f, 0.f, 0.f};

#pragma unroll
    for (int chunk = 0; chunk < NCH; ++chunk) {
        f16x8 afrag;
        if constexpr (F16IN) {
            const _Float16* aptr = (const _Float16*)Xv + (size_t)arow * K + lgrp * 8;
            afrag = *reinterpret_cast<const f16x8*>(aptr + chunk * 32);
        } else {
            const float* aptr = (const float*)Xv + (size_t)arow * K + lgrp * 8;
            float4 va = *reinterpret_cast<const float4*>(aptr + chunk * 32);
            float4 vb = *reinterpret_cast<const float4*>(aptr + chunk * 32 + 4);
            afrag = (f16x8){(_Float16)va.x, (_Float16)va.y, (_Float16)va.z, (_Float16)va.w,
                            (_Float16)vb.x, (_Float16)vb.y, (_Float16)vb.z, (_Float16)vb.w};
        }
#pragma unroll
        for (int ct = 0; ct < 8; ++ct) {
            f16x8 bfrag = *reinterpret_cast<const f16x8*>(&wlds[((ct * NCH + chunk) * 64 + lane) * 8]);
            acc[ct] = __builtin_amdgcn_mfma_f32_16x16x32_f16(afrag, bfrag, acc[ct], 0, 0, 0);
        }
    }

    float asv[8], adv[8];
#pragma unroll
    for (int ct = 0; ct < 8; ++ct) {
        asv[ct] = as_[ct * 16 + lcol];
        adv[ct] = ad_[ct * 16 + lcol];
    }

#pragma unroll
    for (int r = 0; r < 4; ++r) {
        int grow = row0 + lgrp * 4 + r;
        float s0 = 0.f, s1 = 0.f, d0 = 0.f, d1 = 0.f;
#pragma unroll
        for (int ct = 0; ct < 8; ++ct) {
            float v = acc[ct][r];
            if (grow < M) H16[(size_t)grow * 128 + ct * 16 + lcol] = (_Float16)v;
            if (ct < 4) { s0 += v * asv[ct]; d0 += v * adv[ct]; }
            else        { s1 += v * asv[ct]; d1 += v * adv[ct]; }
        }
#pragma unroll
        for (int m = 1; m < 16; m <<= 1) {
            s0 += __shfl_xor(s0, m);
            s1 += __shfl_xor(s1, m);
            d0 += __shfl_xor(d0, m);
            d1 += __shfl_xor(d1, m);
        }
        if (lcol == 0 && grow < M) {
            a_src[grow] = make_float2(s0, s1);
            a_dst[grow] = make_float2(d0, d1);
        }
    }
}

// ============================ fused logit + aggregate + self-mean ============================
// R15's proven depth-4 structure (2 subgroups x 32 lanes, lane = f16x4 / 8B gather,
// 2 edges per stage, pA..pD named-reg rotating prefetch). Change vs R15: den is now
// accumulated per-lane in the chunk HEADER (like sae) and reduced in the final
// butterfly — removes 1 VALU from every stage. Self-loop terms added ONCE,
// post-combine (R12 lesson). ex-broadcast slot sl_ <= 63 never wraps; slots >= m
// read inactive lanes' ex = 0. Prefetch slot (sl_+8)&63 may wrap: address valid,
// contribution zeroed by the ex=0 guard.
#define AGG_STAGE(PREG, II)                                                        \
    do {                                                                           \
        int sl_ = 2 * (II) + sub;                                                  \
        float e0b_ = __shfl(ex0, sl_);                                             \
        float e1b_ = __shfl(ex1, sl_);                                             \
        float exu_ = h1sel ? e1b_ : e0b_;                                          \
        int svn_ = __shfl(sv, (sl_ + 8) & 63);                                     \
        acc0 = fmaf(exu_, (float)PREG.x, acc0);                                    \
        acc1 = fmaf(exu_, (float)PREG.y, acc1);                                    \
        acc2 = fmaf(exu_, (float)PREG.z, acc2);                                    \
        acc3 = fmaf(exu_, (float)PREG.w, acc3);                                    \
        PREG = *reinterpret_cast<const f16x4*>(hb + ((size_t)(unsigned)svn_ << 8)); \
    } while (0)

__global__ void aggregate_kernel(const int* __restrict__ csr_off, const uint4* __restrict__ recs,
                                 const float2* __restrict__ a_src, const float2* __restrict__ a_dst,
                                 const _Float16* __restrict__ H16, const float* __restrict__ bias,
                                 float* __restrict__ out32, _Float16* __restrict__ out16,
                                 int layer, int do_relu) {
    int wid = (blockIdx.x * blockDim.x + threadIdx.x) >> 6;
    int lane = threadIdx.x & 63;
    if (wid >= N_NODES) return;
    const int n = wid;
    const int q = lane & 31;       // channel-slot group: f16 indices q*4..q*4+3
    const int sub = lane >> 5;     // which edge of the pair
    const bool h1sel = q >= 16;    // slots 64..127 = head1
    const char* hb = reinterpret_cast<const char*>(H16) + q * 8;

    float2 adn = a_dst[n];
    float2 asn = a_src[n];
    int b = csr_off[n], e = csr_off[n + 1];

    float acc0 = 0.f, acc1 = 0.f, acc2 = 0.f, acc3 = 0.f;
    float den0l = 0.f, den1l = 0.f;   // per-lane den partials (header-accumulated)
    float sae0 = 0.f, sae1 = 0.f;

    for (int base = b; base < e; base += 64) {
        int j = base + lane;
        bool act = j < e;
        int sv = n;
        float ex0 = 0.f, ex1 = 0.f;
        if (act) {
            uint4 rec = recs[j];
            sv = (int)rec.x;
            unsigned aeu = layer ? rec.z : rec.y;
            f16x2 aev = __builtin_bit_cast(f16x2, aeu);
            float ael0 = (float)aev.x, ael1 = (float)aev.y;
            sae0 += ael0;
            sae1 += ael1;
            float2 asv = a_src[sv];
            float q0 = asv.x + adn.x + ael0;
            float q1 = asv.y + adn.y + ael1;
            q0 = (q0 > 0.f) ? q0 : NEG_SLOPE * q0;
            q1 = (q1 > 0.f) ? q1 : NEG_SLOPE * q1;
            ex0 = __expf(q0);
            ex1 = __expf(q1);
            den0l += ex0;
            den1l += ex1;
        }

        int m = e - base;
        if (m > 64) m = 64;
        int nit = (m + 1) >> 1;  // 2 edges per stage
        f16x4 pA, pB, pC, pD;
        int s_;
        s_ = __shfl(sv, sub);     pA = *reinterpret_cast<const f16x4*>(hb + ((size_t)(unsigned)s_ << 8));
        s_ = __shfl(sv, 2 + sub); pB = *reinterpret_cast<const f16x4*>(hb + ((size_t)(unsigned)s_ << 8));
        s_ = __shfl(sv, 4 + sub); pC = *reinterpret_cast<const f16x4*>(hb + ((size_t)(unsigned)s_ << 8));
        s_ = __shfl(sv, 6 + sub); pD = *reinterpret_cast<const f16x4*>(hb + ((size_t)(unsigned)s_ << 8));
        for (int i = 0; i < nit; i += 4) {
            AGG_STAGE(pA, i);
            AGG_STAGE(pB, i + 1);
            AGG_STAGE(pC, i + 2);
            AGG_STAGE(pD, i + 3);
        }
    }

    // combine the two sub-groups FIRST (disjoint edge halves)
    acc0 += __shfl_xor(acc0, 32);
    acc1 += __shfl_xor(acc1, 32);
    acc2 += __shfl_xor(acc2, 32);
    acc3 += __shfl_xor(acc3, 32);

    // butterfly den + sae partials (full wave)
#pragma unroll
    for (int m2 = 32; m2; m2 >>= 1) {
        sae0 += __shfl_xor(sae0, m2);
        sae1 += __shfl_xor(sae1, m2);
        den0l += __shfl_xor(den0l, m2);
        den1l += __shfl_xor(den1l, m2);
    }

    // self-loop: ae_self = mean of incoming ae (0 if no edges); added ONCE, post-combine
    int deg = e - b;
    float invd = (deg > 0) ? (1.f / (float)deg) : 0.f;
    float l0 = asn.x + adn.x + sae0 * invd;
    float l1 = asn.y + adn.y + sae1 * invd;
    l0 = (l0 > 0.f) ? l0 : NEG_SLOPE * l0;
    l1 = (l1 > 0.f) ? l1 : NEG_SLOPE * l1;
    float exs0 = __expf(l0), exs1 = __expf(l1);
    float exsu = h1sel ? exs1 : exs0;
    float den = (h1sel ? den1l : den0l) + exsu;
    f16x4 hs = *reinterpret_cast<const f16x4*>(hb + ((size_t)(unsigned)n << 8));
    acc0 = fmaf(exsu, (float)hs.x, acc0);
    acc1 = fmaf(exsu, (float)hs.y, acc1);
    acc2 = fmaf(exsu, (float)hs.z, acc2);
    acc3 = fmaf(exsu, (float)hs.w, acc3);

    float invden = 1.f / (den + 1e-16f);
    float r0 = acc0 * invden;
    float r1 = acc1 * invden;
    float r2 = acc2 * invden;
    float r3 = acc3 * invden;
    // head combine: lane q<16 (head0 ch q*4..+3) pairs with lane q+16 (head1 same ch)
    float t0 = __shfl_xor(r0, 16);
    float t1 = __shfl_xor(r1, 16);
    float t2 = __shfl_xor(r2, 16);
    float t3 = __shfl_xor(r3, 16);
    if (lane < 16) {
        float4 bv = *reinterpret_cast<const float4*>(bias + q * 4);
        float o0 = 0.5f * (r0 + t0) + bv.x;
        float o1 = 0.5f * (r1 + t1) + bv.y;
        float o2 = 0.5f * (r2 + t2) + bv.z;
        float o3 = 0.5f * (r3 + t3) + bv.w;
        if (do_relu) {
            o0 = fmaxf(o0, 0.f); o1 = fmaxf(o1, 0.f);
            o2 = fmaxf(o2, 0.f); o3 = fmaxf(o3, 0.f);
        }
        if (out32) {
            float4 ov = {o0, o1, o2, o3};
            *reinterpret_cast<float4*>(out32 + (size_t)n * 64 + q * 4) = ov;
        }
        if (out16) {
            f16x4 ov16 = {(_Float16)o0, (_Float16)o1, (_Float16)o2, (_Float16)o3};
            *reinterpret_cast<f16x4*>(out16 + (size_t)n * 64 + q * 4) = ov16;
        }
    }
}

// ============================ launch ============================
extern "C" void kernel_launch(void* const* d_in, const int* in_sizes, int n_in,
                              void* d_out, int out_size, void* d_ws, size_t ws_size,
                              hipStream_t stream) {
    const float* x = (const float*)d_in[0];
    const int* ei = (const int*)d_in[1];
    const float* edge_attr = (const float*)d_in[2];
    const float* W1 = (const float*)d_in[3];
    const float* We1 = (const float*)d_in[4];
    const float* as1 = (const float*)d_in[5];
    const float* ad1 = (const float*)d_in[6];
    const float* ae1 = (const float*)d_in[7];
    const float* b1 = (const float*)d_in[8];
    const float* W2 = (const float*)d_in[9];
    const float* We2 = (const float*)d_in[10];
    const float* as2 = (const float*)d_in[11];
    const float* ad2 = (const float*)d_in[12];
    const float* ae2 = (const float*)d_in[13];
    const float* b2 = (const float*)d_in[14];
    float* out = (float*)d_out;

    char* ws = (char*)d_ws;
    size_t off = 0;
    auto alloc = [&](size_t bytes) -> void* {
        void* p = ws + off;
        off += (bytes + 255) & ~(size_t)255;
        return p;
    };
    int* cnt = (int*)alloc((size_t)N_NODES * 4);
    int* csr_off = (int*)alloc(((size_t)N_NODES + 1) * 4);
    int* rank = (int*)alloc((size_t)N_EDGES * 4);
    int* excl = (int*)alloc((size_t)N_NODES * 4);
    int* bsums = (int*)alloc(256 * 4);
    int* bsums2 = (int*)alloc(256 * 4);
    uint4* recs = (uint4*)alloc((size_t)N_EDGES * 16);
    _Float16* H16 = (_Float16*)alloc((size_t)N_NODES * 128 * 2);
    _Float16* h1_16 = (_Float16*)alloc((size_t)N_NODES * 64 * 2);
    float* a_src = (float*)alloc((size_t)N_NODES * 2 * 4);
    float* a_dst = (float*)alloc((size_t)N_NODES * 2 * 4);
    float* w_e = (float*)alloc(64 * 4);

    const int nb = (N_NODES + 255) / 256;
    const int eb = (N_EDGES + 255) / 256;

    // ---- CSR (atomic only in count; its return value = rank) ----
    zero_we2_kernel<<<nb, 256, 0, stream>>>(cnt, We1, ae1, We2, ae2, w_e);
    count_rank_kernel<<<eb, 256, 0, stream>>>(ei, cnt, rank);
    scan_block_kernel<<<nb, 256, 0, stream>>>(cnt, excl, bsums, N_NODES);
    scan_block_kernel<<<1, 256, 0, stream>>>(bsums, bsums2, nullptr, nb);
    scan_add_kernel<<<nb, 256, 0, stream>>>(excl, bsums2, csr_off, N_NODES, N_EDGES);
    scatter_pack_kernel<<<eb, 256, 0, stream>>>(ei, edge_attr, w_e, csr_off, rank, recs);

    const int nodeWaveBlocks = (N_NODES * 64 + 255) / 256;
    const int gemmBlocks = (N_NODES + 63) / 64;

    // ---- layer 1: IN=128 -> HID=64, H=2, relu; h1 written f16 only ----
    gemm_att_kernel<128, false><<<gemmBlocks, 256, 0, stream>>>(x, W1, as1, ad1, H16,
                                                                (float2*)a_src, (float2*)a_dst, N_NODES);
    aggregate_kernel<<<nodeWaveBlocks, 256, 0, stream>>>(csr_off, recs,
                                                         (const float2*)a_src, (const float2*)a_dst,
                                                         H16, b1, nullptr, h1_16, 0, 1);

    // ---- layer 2: HID=64 -> OUT=64, H=2, no relu ----
    gemm_att_kernel<64, true><<<gemmBlocks, 256, 0, stream>>>(h1_16, W2, as2, ad2, H16,
                                                              (float2*)a_src, (float2*)a_dst, N_NODES);
    aggregate_kernel<<<nodeWaveBlocks, 256, 0, stream>>>(csr_off, recs,
                                                         (const float2*)a_src, (const float2*)a_dst,
                                                         H16, b2, out, nullptr, 1, 0);
}

// Round 18
// 175.574 us; speedup vs baseline: 1.1186x; 1.0472x over previous
//
#include <hip/hip_runtime.h>

#define N_NODES 50000
#define N_EDGES 800000
#define EDIM 16
#define NEG_SLOPE 0.2f

typedef _Float16 f16x8 __attribute__((ext_vector_type(8)));
typedef _Float16 f16x4 __attribute__((ext_vector_type(4)));
typedef _Float16 f16x2 __attribute__((ext_vector_type(2)));
typedef float f32x4 __attribute__((ext_vector_type(4)));

// ============================ CSR build ============================
// zero cnt + compute w_e in one launch (block 0, lanes 0-63 do w_e)
// w_e layout: [0:16) l1h0, [16:32) l1h1, [32:48) l2h0, [48:64) l2h1
__global__ void zero_we2_kernel(int* __restrict__ cnt,
                                const float* __restrict__ We1, const float* __restrict__ ae1,
                                const float* __restrict__ We2, const float* __restrict__ ae2,
                                float* __restrict__ w_e) {
    int gid = blockIdx.x * blockDim.x + threadIdx.x;
    if (gid < N_NODES) cnt[gid] = 0;
    if (blockIdx.x == 0 && threadIdx.x < 64) {
        int idx = threadIdx.x;
        const float* We = (idx < 32) ? We1 : We2;
        const float* ae = (idx < 32) ? ae1 : ae2;
        int i = idx & 31;
        int h = i >> 4, d = i & 15;
        float s = 0.f;
        for (int c = 0; c < 64; ++c) s += We[d * 128 + h * 64 + c] * ae[h * 64 + c];
        w_e[idx] = s;
    }
}

// count + per-edge rank (the atomic's return value IS the rank within dst)
__global__ void count_rank_kernel(const int* __restrict__ ei, int* __restrict__ cnt,
                                  int* __restrict__ rank) {
    int e = blockIdx.x * blockDim.x + threadIdx.x;
    if (e < N_EDGES) rank[e] = atomicAdd(&cnt[ei[N_EDGES + e]], 1);
}

__global__ void scan_block_kernel(const int* __restrict__ in, int* __restrict__ excl,
                                  int* __restrict__ bsums, int n) {
    __shared__ int sh[256];
    int tid = threadIdx.x;
    int gid = blockIdx.x * 256 + tid;
    int v = (gid < n) ? in[gid] : 0;
    sh[tid] = v;
    __syncthreads();
    for (int off = 1; off < 256; off <<= 1) {
        int t = (tid >= off) ? sh[tid - off] : 0;
        __syncthreads();
        sh[tid] += t;
        __syncthreads();
    }
    if (gid < n) excl[gid] = sh[tid] - v;
    if (bsums != nullptr && tid == 255) bsums[blockIdx.x] = sh[tid];
}

__global__ void scan_add_kernel(const int* __restrict__ excl, const int* __restrict__ bs2,
                                int* __restrict__ csr_off, int n, int total) {
    int gid = blockIdx.x * 256 + threadIdx.x;
    if (gid < n) csr_off[gid] = excl[gid] + bs2[gid >> 8];
    if (gid == 0) csr_off[n] = total;
}

// atomic-free scatter: pos = csr_off[d] + rank[e]; ONE packed 16B record per edge
// rec = {src, f16x2(ae1 h0,h1), f16x2(ae2 h0,h1), 0}
__global__ void scatter_pack_kernel(const int* __restrict__ ei, const float* __restrict__ edge_attr,
                                    const float* __restrict__ w_e, const int* __restrict__ csr_off,
                                    const int* __restrict__ rank, uint4* __restrict__ recs) {
    int e = blockIdx.x * blockDim.x + threadIdx.x;
    if (e >= N_EDGES) return;
    int s = ei[e];
    int d = ei[N_EDGES + e];
    const float* ea = edge_attr + (size_t)e * 16;
    float4 dd = make_float4(0.f, 0.f, 0.f, 0.f);
#pragma unroll
    for (int q = 0; q < 4; ++q) {
        float4 v = *reinterpret_cast<const float4*>(ea + q * 4);
        float4 wa = *reinterpret_cast<const float4*>(w_e + q * 4);
        float4 wb = *reinterpret_cast<const float4*>(w_e + 16 + q * 4);
        float4 wc = *reinterpret_cast<const float4*>(w_e + 32 + q * 4);
        float4 wd = *reinterpret_cast<const float4*>(w_e + 48 + q * 4);
        dd.x += v.x * wa.x + v.y * wa.y + v.z * wa.z + v.w * wa.w;
        dd.y += v.x * wb.x + v.y * wb.y + v.z * wb.z + v.w * wb.w;
        dd.z += v.x * wc.x + v.y * wc.y + v.z * wc.z + v.w * wc.w;
        dd.w += v.x * wd.x + v.y * wd.y + v.z * wd.z + v.w * wd.w;
    }
    f16x2 p1 = {(_Float16)dd.x, (_Float16)dd.y};
    f16x2 p2 = {(_Float16)dd.z, (_Float16)dd.w};
    int pos = csr_off[d] + rank[e];
    uint4 rec;
    rec.x = (unsigned)s;
    rec.y = __builtin_bit_cast(unsigned int, p1);
    rec.z = __builtin_bit_cast(unsigned int, p2);
    rec.w = 0u;
    recs[pos] = rec;
}

// ============================ fused MFMA GEMM + attdot ============================
// H = X[M,K] @ W[K,128]; X read as f32 (cast) or f16 per F16IN. Writes H16 + a_src/a_dst.
// Layouts (guide §3, m89/m156): A: row=lane&15, k=8*(lane>>4)+j
//                               B: col=lane&15, k=8*(lane>>4)+j
//                               D: col=lane&15, row=4*(lane>>4)+reg
template <int K, bool F16IN>
__global__ __launch_bounds__(256) void gemm_att_kernel(const void* __restrict__ Xv,
                                                       const float* __restrict__ W,
                                                       const float* __restrict__ as_,
                                                       const float* __restrict__ ad_,
                                                       _Float16* __restrict__ H16,
                                                       float2* __restrict__ a_src,
                                                       float2* __restrict__ a_dst, int M) {
    constexpr int NCH = K / 32;
    __shared__ _Float16 wlds[8 * NCH * 64 * 8];  // [ct][chunk][lane][j]
    const int tid = threadIdx.x;

    for (int idx = tid; idx < K * 128; idx += 256) {
        int k = idx >> 7, c = idx & 127;
        int ct = c >> 4, cl = c & 15;
        int chunk = k >> 5, grp = (k >> 3) & 3, j = k & 7;
        wlds[(((ct * NCH) + chunk) * 64 + (grp * 16 + cl)) * 8 + j] = (_Float16)W[idx];
    }
    __syncthreads();

    const int wv = tid >> 6, lane = tid & 63;
    const int lcol = lane & 15, lgrp = lane >> 4;
    const int row0 = blockIdx.x * 64 + wv * 16;
    int arow = row0 + lcol;
    if (arow >= M) arow = M - 1;

    f32x4 acc[8];
#pragma unroll
    for (int ct = 0; ct < 8; ++ct) acc[ct] = (f32x4){0.f, 0.f, 0.f, 0.f};

#pragma unroll
    for (int chunk = 0; chunk < NCH; ++chunk) {
        f16x8 afrag;
        if constexpr (F16IN) {
            const _Float16* aptr = (const _Float16*)Xv + (size_t)arow * K + lgrp * 8;
            afrag = *reinterpret_cast<const f16x8*>(aptr + chunk * 32);
        } else {
            const float* aptr = (const float*)Xv + (size_t)arow * K + lgrp * 8;
            float4 va = *reinterpret_cast<const float4*>(aptr + chunk * 32);
            float4 vb = *reinterpret_cast<const float4*>(aptr + chunk * 32 + 4);
            afrag = (f16x8){(_Float16)va.x, (_Float16)va.y, (_Float16)va.z, (_Float16)va.w,
                            (_Float16)vb.x, (_Float16)vb.y, (_Float16)vb.z, (_Float16)vb.w};
        }
#pragma unroll
        for (int ct = 0; ct < 8; ++ct) {
            f16x8 bfrag = *reinterpret_cast<const f16x8*>(&wlds[((ct * NCH + chunk) * 64 + lane) * 8]);
            acc[ct] = __builtin_amdgcn_mfma_f32_16x16x32_f16(afrag, bfrag, acc[ct], 0, 0, 0);
        }
    }

    float asv[8], adv[8];
#pragma unroll
    for (int ct = 0; ct < 8; ++ct) {
        asv[ct] = as_[ct * 16 + lcol];
        adv[ct] = ad_[ct * 16 + lcol];
    }

#pragma unroll
    for (int r = 0; r < 4; ++r) {
        int grow = row0 + lgrp * 4 + r;
        float s0 = 0.f, s1 = 0.f, d0 = 0.f, d1 = 0.f;
#pragma unroll
        for (int ct = 0; ct < 8; ++ct) {
            float v = acc[ct][r];
            if (grow < M) H16[(size_t)grow * 128 + ct * 16 + lcol] = (_Float16)v;
            if (ct < 4) { s0 += v * asv[ct]; d0 += v * adv[ct]; }
            else        { s1 += v * asv[ct]; d1 += v * adv[ct]; }
        }
#pragma unroll
        for (int m = 1; m < 16; m <<= 1) {
            s0 += __shfl_xor(s0, m);
            s1 += __shfl_xor(s1, m);
            d0 += __shfl_xor(d0, m);
            d1 += __shfl_xor(d1, m);
        }
        if (lcol == 0 && grow < M) {
            a_src[grow] = make_float2(s0, s1);
            a_dst[grow] = make_float2(d0, d1);
        }
    }
}

// ============================ fused logit + aggregate + self-mean ============================
// R15's measured-best aggregate, verbatim: 2 subgroups x 32 lanes, lane = f16x4 / 8B
// gather, 2 edges per stage, DEPTH-4 rotating prefetch (pA..pD named regs, rule #20),
// den accumulated in-loop from the head-selected broadcast and folded into the single
// shfl_xor(32) subgroup combine (VGPR 32, ~64% occupancy — the R17 header-den variant
// cost 4 VGPR / 5% occ and regressed). Self-loop terms added ONCE, post-combine (R12
// lesson). ex-broadcast slot sl_ <= 63 never wraps; slots >= m read inactive lanes'
// ex = 0. Prefetch slot (sl_+8)&63 may wrap: address valid, contribution zeroed by
// the ex=0 guard.
#define AGG_STAGE(PREG, II)                                                        \
    do {                                                                           \
        int sl_ = 2 * (II) + sub;                                                  \
        float e0b_ = __shfl(ex0, sl_);                                             \
        float e1b_ = __shfl(ex1, sl_);                                             \
        float exu_ = h1sel ? e1b_ : e0b_;                                          \
        int svn_ = __shfl(sv, (sl_ + 8) & 63);                                     \
        den += exu_;                                                               \
        acc0 = fmaf(exu_, (float)PREG.x, acc0);                                    \
        acc1 = fmaf(exu_, (float)PREG.y, acc1);                                    \
        acc2 = fmaf(exu_, (float)PREG.z, acc2);                                    \
        acc3 = fmaf(exu_, (float)PREG.w, acc3);                                    \
        PREG = *reinterpret_cast<const f16x4*>(hb + ((size_t)(unsigned)svn_ << 8)); \
    } while (0)

__global__ void aggregate_kernel(const int* __restrict__ csr_off, const uint4* __restrict__ recs,
                                 const float2* __restrict__ a_src, const float2* __restrict__ a_dst,
                                 const _Float16* __restrict__ H16, const float* __restrict__ bias,
                                 float* __restrict__ out32, _Float16* __restrict__ out16,
                                 int layer, int do_relu) {
    int wid = (blockIdx.x * blockDim.x + threadIdx.x) >> 6;
    int lane = threadIdx.x & 63;
    if (wid >= N_NODES) return;
    const int n = wid;
    const int q = lane & 31;       // channel-slot group: f16 indices q*4..q*4+3
    const int sub = lane >> 5;     // which edge of the pair
    const bool h1sel = q >= 16;    // slots 64..127 = head1
    const char* hb = reinterpret_cast<const char*>(H16) + q * 8;

    float2 adn = a_dst[n];
    float2 asn = a_src[n];
    int b = csr_off[n], e = csr_off[n + 1];

    float acc0 = 0.f, acc1 = 0.f, acc2 = 0.f, acc3 = 0.f;
    float den = 0.f;
    float sae0 = 0.f, sae1 = 0.f;

    for (int base = b; base < e; base += 64) {
        int j = base + lane;
        bool act = j < e;
        int sv = n;
        float ex0 = 0.f, ex1 = 0.f;
        if (act) {
            uint4 rec = recs[j];
            sv = (int)rec.x;
            unsigned aeu = layer ? rec.z : rec.y;
            f16x2 aev = __builtin_bit_cast(f16x2, aeu);
            float ael0 = (float)aev.x, ael1 = (float)aev.y;
            sae0 += ael0;
            sae1 += ael1;
            float2 asv = a_src[sv];
            float q0 = asv.x + adn.x + ael0;
            float q1 = asv.y + adn.y + ael1;
            q0 = (q0 > 0.f) ? q0 : NEG_SLOPE * q0;
            q1 = (q1 > 0.f) ? q1 : NEG_SLOPE * q1;
            ex0 = __expf(q0);
            ex1 = __expf(q1);
        }

        int m = e - base;
        if (m > 64) m = 64;
        int nit = (m + 1) >> 1;  // 2 edges per stage
        f16x4 pA, pB, pC, pD;
        int s_;
        s_ = __shfl(sv, sub);     pA = *reinterpret_cast<const f16x4*>(hb + ((size_t)(unsigned)s_ << 8));
        s_ = __shfl(sv, 2 + sub); pB = *reinterpret_cast<const f16x4*>(hb + ((size_t)(unsigned)s_ << 8));
        s_ = __shfl(sv, 4 + sub); pC = *reinterpret_cast<const f16x4*>(hb + ((size_t)(unsigned)s_ << 8));
        s_ = __shfl(sv, 6 + sub); pD = *reinterpret_cast<const f16x4*>(hb + ((size_t)(unsigned)s_ << 8));
        for (int i = 0; i < nit; i += 4) {
            AGG_STAGE(pA, i);
            AGG_STAGE(pB, i + 1);
            AGG_STAGE(pC, i + 2);
            AGG_STAGE(pD, i + 3);
        }
    }

    // combine the two sub-groups FIRST (disjoint edge halves); den rides along
    acc0 += __shfl_xor(acc0, 32);
    acc1 += __shfl_xor(acc1, 32);
    acc2 += __shfl_xor(acc2, 32);
    acc3 += __shfl_xor(acc3, 32);
    den += __shfl_xor(den, 32);

    // self-loop: ae_self = mean of incoming ae (0 if no edges); added ONCE, post-combine
#pragma unroll
    for (int m2 = 32; m2; m2 >>= 1) {
        sae0 += __shfl_xor(sae0, m2);
        sae1 += __shfl_xor(sae1, m2);
    }
    int deg = e - b;
    float invd = (deg > 0) ? (1.f / (float)deg) : 0.f;
    float l0 = asn.x + adn.x + sae0 * invd;
    float l1 = asn.y + adn.y + sae1 * invd;
    l0 = (l0 > 0.f) ? l0 : NEG_SLOPE * l0;
    l1 = (l1 > 0.f) ? l1 : NEG_SLOPE * l1;
    float exs0 = __expf(l0), exs1 = __expf(l1);
    float exsu = h1sel ? exs1 : exs0;
    den += exsu;
    f16x4 hs = *reinterpret_cast<const f16x4*>(hb + ((size_t)(unsigned)n << 8));
    acc0 = fmaf(exsu, (float)hs.x, acc0);
    acc1 = fmaf(exsu, (float)hs.y, acc1);
    acc2 = fmaf(exsu, (float)hs.z, acc2);
    acc3 = fmaf(exsu, (float)hs.w, acc3);

    float invden = 1.f / (den + 1e-16f);
    float r0 = acc0 * invden;
    float r1 = acc1 * invden;
    float r2 = acc2 * invden;
    float r3 = acc3 * invden;
    // head combine: lane q<16 (head0 ch q*4..+3) pairs with lane q+16 (head1 same ch)
    float t0 = __shfl_xor(r0, 16);
    float t1 = __shfl_xor(r1, 16);
    float t2 = __shfl_xor(r2, 16);
    float t3 = __shfl_xor(r3, 16);
    if (lane < 16) {
        float4 bv = *reinterpret_cast<const float4*>(bias + q * 4);
        float o0 = 0.5f * (r0 + t0) + bv.x;
        float o1 = 0.5f * (r1 + t1) + bv.y;
        float o2 = 0.5f * (r2 + t2) + bv.z;
        float o3 = 0.5f * (r3 + t3) + bv.w;
        if (do_relu) {
            o0 = fmaxf(o0, 0.f); o1 = fmaxf(o1, 0.f);
            o2 = fmaxf(o2, 0.f); o3 = fmaxf(o3, 0.f);
        }
        if (out32) {
            float4 ov = {o0, o1, o2, o3};
            *reinterpret_cast<float4*>(out32 + (size_t)n * 64 + q * 4) = ov;
        }
        if (out16) {
            f16x4 ov16 = {(_Float16)o0, (_Float16)o1, (_Float16)o2, (_Float16)o3};
            *reinterpret_cast<f16x4*>(out16 + (size_t)n * 64 + q * 4) = ov16;
        }
    }
}

// ============================ launch ============================
extern "C" void kernel_launch(void* const* d_in, const int* in_sizes, int n_in,
                              void* d_out, int out_size, void* d_ws, size_t ws_size,
                              hipStream_t stream) {
    const float* x = (const float*)d_in[0];
    const int* ei = (const int*)d_in[1];
    const float* edge_attr = (const float*)d_in[2];
    const float* W1 = (const float*)d_in[3];
    const float* We1 = (const float*)d_in[4];
    const float* as1 = (const float*)d_in[5];
    const float* ad1 = (const float*)d_in[6];
    const float* ae1 = (const float*)d_in[7];
    const float* b1 = (const float*)d_in[8];
    const float* W2 = (const float*)d_in[9];
    const float* We2 = (const float*)d_in[10];
    const float* as2 = (const float*)d_in[11];
    const float* ad2 = (const float*)d_in[12];
    const float* ae2 = (const float*)d_in[13];
    const float* b2 = (const float*)d_in[14];
    float* out = (float*)d_out;

    char* ws = (char*)d_ws;
    size_t off = 0;
    auto alloc = [&](size_t bytes) -> void* {
        void* p = ws + off;
        off += (bytes + 255) & ~(size_t)255;
        return p;
    };
    int* cnt = (int*)alloc((size_t)N_NODES * 4);
    int* csr_off = (int*)alloc(((size_t)N_NODES + 1) * 4);
    int* rank = (int*)alloc((size_t)N_EDGES * 4);
    int* excl = (int*)alloc((size_t)N_NODES * 4);
    int* bsums = (int*)alloc(256 * 4);
    int* bsums2 = (int*)alloc(256 * 4);
    uint4* recs = (uint4*)alloc((size_t)N_EDGES * 16);
    _Float16* H16 = (_Float16*)alloc((size_t)N_NODES * 128 * 2);
    _Float16* h1_16 = (_Float16*)alloc((size_t)N_NODES * 64 * 2);
    float* a_src = (float*)alloc((size_t)N_NODES * 2 * 4);
    float* a_dst = (float*)alloc((size_t)N_NODES * 2 * 4);
    float* w_e = (float*)alloc(64 * 4);

    const int nb = (N_NODES + 255) / 256;
    const int eb = (N_EDGES + 255) / 256;

    // ---- CSR (atomic only in count; its return value = rank) ----
    zero_we2_kernel<<<nb, 256, 0, stream>>>(cnt, We1, ae1, We2, ae2, w_e);
    count_rank_kernel<<<eb, 256, 0, stream>>>(ei, cnt, rank);
    scan_block_kernel<<<nb, 256, 0, stream>>>(cnt, excl, bsums, N_NODES);
    scan_block_kernel<<<1, 256, 0, stream>>>(bsums, bsums2, nullptr, nb);
    scan_add_kernel<<<nb, 256, 0, stream>>>(excl, bsums2, csr_off, N_NODES, N_EDGES);
    scatter_pack_kernel<<<eb, 256, 0, stream>>>(ei, edge_attr, w_e, csr_off, rank, recs);

    const int nodeWaveBlocks = (N_NODES * 64 + 255) / 256;
    const int gemmBlocks = (N_NODES + 63) / 64;

    // ---- layer 1: IN=128 -> HID=64, H=2, relu; h1 written f16 only ----
    gemm_att_kernel<128, false><<<gemmBlocks, 256, 0, stream>>>(x, W1, as1, ad1, H16,
                                                                (float2*)a_src, (float2*)a_dst, N_NODES);
    aggregate_kernel<<<nodeWaveBlocks, 256, 0, stream>>>(csr_off, recs,
                                                         (const float2*)a_src, (const float2*)a_dst,
                                                         H16, b1, nullptr, h1_16, 0, 1);

    // ---- layer 2: HID=64 -> OUT=64, H=2, no relu ----
    gemm_att_kernel<64, true><<<gemmBlocks, 256, 0, stream>>>(h1_16, W2, as2, ad2, H16,
                                                              (float2*)a_src, (float2*)a_dst, N_NODES);
    aggregate_kernel<<<nodeWaveBlocks, 256, 0, stream>>>(csr_off, recs,
                                                         (const float2*)a_src, (const float2*)a_dst,
                                                         H16, b2, out, nullptr, 1, 0);
}